// Round 15
// baseline (2939.286 us; speedup 1.0000x reference)
//
#include <hip/hip_runtime.h>
#include <hip/hip_bf16.h>

#define NB   4
#define NPTS 16384
#define NC   64
#define NM   1024
#define NK   32
#define NCP  67
#define RAD2 0.25f

// workspace offsets in 4-byte units (total ~585k floats = 2.34 MB)
#define OFF_W0T     0u        // 67*128 = 8576
#define OFF_W1T     8576u     // 128*256 = 32768
#define OFF_NEWXYZ  41344u    // 12288
#define OFF_IDXBALL 53632u    // 4*1024*32 = 131072 (int)
#define OFF_CNT     184704u   // 65536 (int)
#define OFF_EMB     250240u   // 384
#define OFF_PW      250624u   // 4096
#define OFF_PE      254720u   // 68608 -> ends 323328
#define OFF_SX      323328u   // 65536 (sorted x, 4 batches)
#define OFF_SY      388864u   // 65536
#define OFF_SZ      454400u   // 65536
#define OFF_SKLO    519936u   // 65536 (u32) -> ends 585472

// output offsets (FLOAT32 elements; d_out is float*)
#define OUT_NEWXYZ 0u
#define OUT_POOLED 12288u
#define OUT_IDX    1060864u

// ---------------- transpose weights ----------------
__global__ __launch_bounds__(256) void k_prepw(const float* __restrict__ w0,
                                               const float* __restrict__ w1,
                                               float* __restrict__ w0t,
                                               float* __restrict__ w1t) {
  int t = blockIdx.x * 256 + threadIdx.x;
  if (t < 128 * NCP) { int o = t / NCP, c = t % NCP; w0t[c * 128 + o] = w0[t]; }
  if (t < 256 * 128) { int o2 = t / 128, o = t % 128; w1t[o * 256 + o2] = w1[t]; }
}

// ---------------- Morton counting-sort (per batch) ----------------
__device__ __forceinline__ unsigned mpart3(unsigned v) {
  return (v & 1u) | ((v & 2u) << 2) | ((v & 4u) << 4);
}
__device__ __forceinline__ unsigned cellof(float x, float y, float z) {
  unsigned qx = (unsigned)fminf(fmaxf((x + 1.0f) * 4.0f, 0.0f), 7.0f);
  unsigned qy = (unsigned)fminf(fmaxf((y + 1.0f) * 4.0f, 0.0f), 7.0f);
  unsigned qz = (unsigned)fminf(fmaxf((z + 1.0f) * 4.0f, 0.0f), 7.0f);
  return mpart3(qx) | (mpart3(qy) << 1) | (mpart3(qz) << 2);
}

__global__ __launch_bounds__(1024) void k_sort(const float* __restrict__ xyz,
                                               float* __restrict__ sx,
                                               float* __restrict__ sy,
                                               float* __restrict__ sz,
                                               unsigned* __restrict__ sklo) {
  const int b = blockIdx.x, t = threadIdx.x;
  const int lane = t & 63, wid = t >> 6;
  const float* xb = xyz + (size_t)b * NPTS * 3;
  __shared__ unsigned s_hist[512], s_off[512], s_wsum[8];
  if (t < 512) s_hist[t] = 0u;
  __syncthreads();
#pragma unroll
  for (int i = 0; i < 16; ++i) {
    int p = t + 1024 * i;
    float x = xb[p * 3 + 0], y = xb[p * 3 + 1], z = xb[p * 3 + 2];
    atomicAdd(&s_hist[cellof(x, y, z)], 1u);
  }
  __syncthreads();
  unsigned v = (t < 512) ? s_hist[t] : 0u;
#pragma unroll
  for (int off = 1; off < 64; off <<= 1) {
    unsigned u = __shfl_up(v, off);
    if (lane >= off) v += u;
  }
  if (t < 512 && lane == 63) s_wsum[wid] = v;
  __syncthreads();
  if (t < 512) {
    unsigned add = 0;
    for (int w = 0; w < wid; ++w) add += s_wsum[w];
    s_off[t] = add + v - s_hist[t];   // exclusive prefix
  }
  __syncthreads();
#pragma unroll
  for (int i = 0; i < 16; ++i) {
    int p = t + 1024 * i;
    float x = xb[p * 3 + 0], y = xb[p * 3 + 1], z = xb[p * 3 + 2];
    unsigned pos = atomicAdd(&s_off[cellof(x, y, z)], 1u);
    sx[b * NPTS + pos] = x;
    sy[b * NPTS + pos] = y;
    sz[b * NPTS + pos] = z;
    sklo[b * NPTS + pos] = 16383u - (unsigned)p;
  }
}

// ---------------- furthest point sampling (bucketized, exact, DPP) ----------
// r14 topology (1 barrier, ping-pong, verified pruning) with ALL shuffle-based
// reduces replaced by DPP (VALU cross-lane, no DS pipe): dependent ds_bpermute
// chains (~120cy each) were the r14 bottleneck. old=src makes every DPP stage
// identity-safe (OOB/masked lanes keep their own value). Key semantics
// unchanged: key = md_bits<<22 | klo<<8 | bucket; (hi,lo) lexicographic max
// == u64 max == (max md, min orig idx) == jnp.argmax. Pruning margin 2^-16
// two-sided covers <=5-ulp d2 rounding (exactness verified r13/r14).
__device__ __forceinline__ unsigned long long umax64(unsigned long long a,
                                                     unsigned long long b) {
  return a > b ? a : b;
}
__device__ __forceinline__ unsigned long long pack_key(float m, unsigned kl,
                                                       int bb) {
  return (((unsigned long long)__float_as_uint(m)) << 22) |
         (((unsigned long long)kl) << 8) | (unsigned long long)(unsigned)bb;
}

#define DPPI(v, CTRL, RM) \
  __builtin_amdgcn_update_dpp((int)(v), (int)(v), CTRL, RM, 0xf, false)

// one stage of (hi,lo) lexicographic max with coord payload (row-local)
#define DPP_PAY(CTRL) { \
  unsigned h2 = (unsigned)DPPI(hi, CTRL, 0xf); \
  unsigned l2 = (unsigned)DPPI(lo, CTRL, 0xf); \
  float x2 = __int_as_float(DPPI(__float_as_int(bwx), CTRL, 0xf)); \
  float y2 = __int_as_float(DPPI(__float_as_int(bwy), CTRL, 0xf)); \
  float z2 = __int_as_float(DPPI(__float_as_int(bwz), CTRL, 0xf)); \
  bool tk = (h2 > hi) || (h2 == hi && l2 > lo); \
  hi = tk ? h2 : hi; lo = tk ? l2 : lo; \
  bwx = tk ? x2 : bwx; bwy = tk ? y2 : bwy; bwz = tk ? z2 : bwz; }

#define DPP_K(CTRL, RM) { \
  unsigned h2 = (unsigned)DPPI(hi, CTRL, RM); \
  unsigned l2 = (unsigned)DPPI(lo, CTRL, RM); \
  bool tk = (h2 > hi) || (h2 == hi && l2 > lo); \
  hi = tk ? h2 : hi; lo = tk ? l2 : lo; }

#define DPP_FMIN(v, CTRL) v = fminf(v, __int_as_float(DPPI(__float_as_int(v), CTRL, 0xf)));
#define DPP_FMAX(v, CTRL) v = fmaxf(v, __int_as_float(DPPI(__float_as_int(v), CTRL, 0xf)));

// full-wave (hi,lo) max -> broadcast to all lanes via readlane(63)
__device__ __forceinline__ unsigned long long wave_max_key(unsigned long long k) {
  unsigned hi = (unsigned)(k >> 32), lo = (unsigned)k;
  DPP_K(0x111, 0xf)   // row_shr:1
  DPP_K(0x112, 0xf)   // row_shr:2
  DPP_K(0x114, 0xf)   // row_shr:4
  DPP_K(0x118, 0xf)   // row_shr:8
  DPP_K(0x142, 0xa)   // row_bcast15 -> rows 1,3
  DPP_K(0x143, 0xc)   // row_bcast31 -> rows 2,3
  hi = (unsigned)__builtin_amdgcn_readlane((int)hi, 63);
  lo = (unsigned)__builtin_amdgcn_readlane((int)lo, 63);
  return ((unsigned long long)hi << 32) | lo;
}

template <bool INIT>
__device__ __forceinline__ void fps_bucket16(
    int bbp, int rl, float lx, float ly, float lz,
    const float* __restrict__ bx, const float* __restrict__ by,
    const float* __restrict__ bz, const unsigned* __restrict__ bk,
    float* s_md, unsigned short* s_klo,
    unsigned long long* skey_out, float4* swin_out,
    float* s_bxl, float* s_bxh, float* s_byl, float* s_byh,
    float* s_bzl, float* s_bzh) {
  const int p0 = bbp * 64 + rl * 4;
  float4 xv = *(const float4*)(bx + p0);
  float4 yv = *(const float4*)(by + p0);
  float4 zv = *(const float4*)(bz + p0);
  float xs[4] = {xv.x, xv.y, xv.z, xv.w};
  float ys[4] = {yv.x, yv.y, yv.z, yv.w};
  float zs[4] = {zv.x, zv.y, zv.z, zv.w};
  unsigned kl[4];
  float md0[4];
  if constexpr (INIT) {
    uint4 kk = *(const uint4*)(bk + p0);
    kl[0] = kk.x; kl[1] = kk.y; kl[2] = kk.z; kl[3] = kk.w;
  } else {
    uint2 kk = *(const uint2*)(&s_klo[p0]);
    kl[0] = kk.x & 0xFFFFu; kl[1] = kk.x >> 16;
    kl[2] = kk.y & 0xFFFFu; kl[3] = kk.y >> 16;
    float4 mv = *(const float4*)(&s_md[p0]);
    md0[0] = mv.x; md0[1] = mv.y; md0[2] = mv.z; md0[3] = mv.w;
  }
  unsigned hi = 0u, lo = 0u;
  float bwx = 0.f, bwy = 0.f, bwz = 0.f;
  float nm[4];
#pragma unroll
  for (int i = 0; i < 4; ++i) {
    float dx = __fsub_rn(xs[i], lx);
    float dy = __fsub_rn(ys[i], ly);
    float dz = __fsub_rn(zs[i], lz);
    float d2 = __fadd_rn(__fadd_rn(__fmul_rn(dx, dx), __fmul_rn(dy, dy)),
                         __fmul_rn(dz, dz));
    float m = INIT ? d2 : fminf(md0[i], d2);
    nm[i] = m;
    unsigned long long key = pack_key(m, kl[i], bbp);
    unsigned h = (unsigned)(key >> 32), l = (unsigned)key;
    bool tk = (h > hi) || (h == hi && l > lo);
    hi = tk ? h : hi; lo = tk ? l : lo;
    bwx = tk ? xs[i] : bwx; bwy = tk ? ys[i] : bwy; bwz = tk ? zs[i] : bwz;
  }
  *(float4*)(&s_md[p0]) = make_float4(nm[0], nm[1], nm[2], nm[3]);
  if constexpr (INIT) {
    uint2 kw;
    kw.x = kl[0] | (kl[1] << 16);
    kw.y = kl[2] | (kl[3] << 16);
    *(uint2*)(&s_klo[p0]) = kw;
  }
  // 16-lane row prefix-argmax with coord payload (pure VALU)
  DPP_PAY(0x111) DPP_PAY(0x112) DPP_PAY(0x114) DPP_PAY(0x118)
  if constexpr (INIT) {
    float xl = fminf(fminf(xs[0], xs[1]), fminf(xs[2], xs[3]));
    float xh = fmaxf(fmaxf(xs[0], xs[1]), fmaxf(xs[2], xs[3]));
    float yl = fminf(fminf(ys[0], ys[1]), fminf(ys[2], ys[3]));
    float yh = fmaxf(fmaxf(ys[0], ys[1]), fmaxf(ys[2], ys[3]));
    float zl = fminf(fminf(zs[0], zs[1]), fminf(zs[2], zs[3]));
    float zh = fmaxf(fmaxf(zs[0], zs[1]), fmaxf(zs[2], zs[3]));
    DPP_FMIN(xl, 0x111) DPP_FMIN(xl, 0x112) DPP_FMIN(xl, 0x114) DPP_FMIN(xl, 0x118)
    DPP_FMAX(xh, 0x111) DPP_FMAX(xh, 0x112) DPP_FMAX(xh, 0x114) DPP_FMAX(xh, 0x118)
    DPP_FMIN(yl, 0x111) DPP_FMIN(yl, 0x112) DPP_FMIN(yl, 0x114) DPP_FMIN(yl, 0x118)
    DPP_FMAX(yh, 0x111) DPP_FMAX(yh, 0x112) DPP_FMAX(yh, 0x114) DPP_FMAX(yh, 0x118)
    DPP_FMIN(zl, 0x111) DPP_FMIN(zl, 0x112) DPP_FMIN(zl, 0x114) DPP_FMIN(zl, 0x118)
    DPP_FMAX(zh, 0x111) DPP_FMAX(zh, 0x112) DPP_FMAX(zh, 0x114) DPP_FMAX(zh, 0x118)
    if (rl == 15) {
      s_bxl[bbp] = xl; s_bxh[bbp] = xh;
      s_byl[bbp] = yl; s_byh[bbp] = yh;
      s_bzl[bbp] = zl; s_bzh[bbp] = zh;
    }
  }
  if (rl == 15) {
    skey_out[bbp] = ((unsigned long long)hi << 32) | lo;
    swin_out[bbp] = make_float4(bwx, bwy, bwz, 0.f);
  }
}

__global__ __launch_bounds__(512) void k_fps(const float* __restrict__ xyz,
                                             const float* __restrict__ sx,
                                             const float* __restrict__ sy,
                                             const float* __restrict__ sz,
                                             const unsigned* __restrict__ sklo,
                                             float* __restrict__ newxyz,
                                             float* __restrict__ out) {
  const int b = blockIdx.x, t = threadIdx.x;
  const int lane = t & 63, w = t >> 6;   // 8 waves
  const int rl = lane & 15, g4 = lane >> 4;
  const float* xb = xyz + (size_t)b * NPTS * 3;
  const float* bx = sx + b * NPTS;
  const float* by = sy + b * NPTS;
  const float* bz = sz + b * NPTS;
  const unsigned* bk = sklo + b * NPTS;
  __shared__ float s_md[NPTS];                      // 64 KiB
  __shared__ unsigned short s_klo[NPTS];            // 32 KiB
  __shared__ float s_bxl[256], s_bxh[256], s_byl[256], s_byh[256],
                   s_bzl[256], s_bzh[256];          // 6 KiB
  __shared__ unsigned long long s_bkey[2][256];     // 4 KiB
  __shared__ float4 s_bwin[2][256];                 // 8 KiB
  float lx = xb[0], ly = xb[1], lz = xb[2];
  if (t == 0) {
    newxyz[(size_t)b * NM * 3 + 0] = lx;
    newxyz[(size_t)b * NM * 3 + 1] = ly;
    newxyz[(size_t)b * NM * 3 + 2] = lz;
    out[OUT_NEWXYZ + (size_t)b * NM * 3 + 0] = lx;
    out[OUT_NEWXYZ + (size_t)b * NM * 3 + 1] = ly;
    out[OUT_NEWXYZ + (size_t)b * NM * 3 + 2] = lz;
    out[OUT_IDX + b * NM] = 0.0f;
  }
  // init: full update vs point 0 (4 groups of 16 per wave, 8 rounds)
#pragma unroll
  for (int r = 0; r < 8; ++r) {
    int bbp = 32 * w + r * 4 + g4;
    fps_bucket16<true>(bbp, rl, lx, ly, lz, bx, by, bz, bk, s_md, s_klo,
                       s_bkey[0], s_bwin[0],
                       s_bxl, s_bxh, s_byl, s_byh, s_bzl, s_bzh);
  }
  // owner lanes cache their bucket's bbox in registers (own-wave RAW)
  float rxl = 0.f, rxh = 0.f, ryl = 0.f, ryh = 0.f, rzl = 0.f, rzh = 0.f;
  if (lane < 32) {
    int bbj = 32 * w + lane;
    rxl = s_bxl[bbj]; rxh = s_bxh[bbj];
    ryl = s_byl[bbj]; ryh = s_byh[bbj];
    rzl = s_bzl[bbj]; rzh = s_bzh[bbj];
  }
  __syncthreads();
  for (int s = 1; s < NM; ++s) {
    const int cur = s & 1, prv = cur ^ 1;
    // fold 256 keys: 4 LDS reads/lane + VALU + DPP wave argmax
    unsigned long long k =
        umax64(umax64(s_bkey[prv][lane], s_bkey[prv][lane + 64]),
               umax64(s_bkey[prv][lane + 128], s_bkey[prv][lane + 192]));
    k = wave_max_key(k);
    const int bbw = (int)(k & 0xFFull);
    float4 wv = s_bwin[prv][bbw];
    lx = wv.x; ly = wv.y; lz = wv.z;
    if (t == 0) {
      const int idx = 16383 - (int)((k >> 8) & 0x3FFFull);
      newxyz[((size_t)b * NM + s) * 3 + 0] = lx;
      newxyz[((size_t)b * NM + s) * 3 + 1] = ly;
      newxyz[((size_t)b * NM + s) * 3 + 2] = lz;
      out[OUT_NEWXYZ + ((size_t)b * NM + s) * 3 + 0] = lx;
      out[OUT_NEWXYZ + ((size_t)b * NM + s) * 3 + 1] = ly;
      out[OUT_NEWXYZ + ((size_t)b * NM + s) * 3 + 2] = lz;
      out[OUT_IDX + b * NM + s] = (float)idx;
    }
    // prune owned buckets (lanes 0..31, bbox in regs); copy pruned -> [cur]
    bool keep = false;
    if (lane < 32) {
      const int bbj = 32 * w + lane;
      unsigned long long kj = s_bkey[prv][bbj];
      float mm = __uint_as_float((unsigned)(kj >> 22));
      float gx = fmaxf(fmaxf(__fsub_rn(rxl, lx), __fsub_rn(lx, rxh)), 0.f);
      float gy = fmaxf(fmaxf(__fsub_rn(ryl, ly), __fsub_rn(ly, ryh)), 0.f);
      float gz = fmaxf(fmaxf(__fsub_rn(rzl, lz), __fsub_rn(lz, rzh)), 0.f);
      float lb = __fadd_rn(__fadd_rn(__fmul_rn(gx, gx), __fmul_rn(gy, gy)),
                           __fmul_rn(gz, gz));
      keep = !(__fmul_rn(lb, 0.999984741f) > __fmul_rn(mm, 1.000015259f));
      if (!keep) {
        s_bkey[cur][bbj] = kj;
        s_bwin[cur][bbj] = s_bwin[prv][bbj];
      }
    }
    unsigned long long mask = __ballot(keep);
    // process kept buckets: 4 groups of 16 lanes per wave per round
    while (mask) {
      unsigned long long m2 = mask;
#pragma unroll
      for (int r = 0; r < 3; ++r) if (r < g4) m2 &= (m2 - 1ull);
      if (m2) {
        int jj = (int)__builtin_ctzll(m2);
        fps_bucket16<false>(32 * w + jj, rl, lx, ly, lz, bx, by, bz, bk,
                            s_md, s_klo, s_bkey[cur], s_bwin[cur],
                            s_bxl, s_bxh, s_byl, s_byh, s_bzl, s_bzh);
      }
#pragma unroll
      for (int r = 0; r < 4; ++r) mask &= (mask - 1ull);
    }
    __syncthreads();
  }
}

// ---------------- ball query: first NK indices with d2<=r2, pad with first ----
__global__ __launch_bounds__(256) void k_ball(const float* __restrict__ xyz,
                                              const float* __restrict__ newxyz,
                                              int* __restrict__ idxball,
                                              int* __restrict__ cnt,
                                              float* __restrict__ emb) {
  __shared__ int s_idx[4][NK];
  const int lane = threadIdx.x & 63, wid = threadIdx.x >> 6;
  const int gid = blockIdx.x * 4 + wid; // (b,m)
  const int b = gid >> 10;
  const float* xb = xyz + (size_t)b * NPTS * 3;
  const float cx = newxyz[gid * 3 + 0];
  const float cy = newxyz[gid * 3 + 1];
  const float cz = newxyz[gid * 3 + 2];
  int total = 0;
  for (int base = 0; base < NPTS && total < NK; base += 64) {
    int n = base + lane;
    float dx = __fsub_rn(xb[n * 3 + 0], cx);
    float dy = __fsub_rn(xb[n * 3 + 1], cy);
    float dz = __fsub_rn(xb[n * 3 + 2], cz);
    float d2 = __fadd_rn(__fadd_rn(__fmul_rn(dx, dx), __fmul_rn(dy, dy)),
                         __fmul_rn(dz, dz));
    bool hit = d2 <= RAD2;
    unsigned long long mask = __ballot(hit);
    int pos = total + (int)__popcll(mask & ((1ull << lane) - 1ull));
    if (hit && pos < NK) s_idx[wid][pos] = n;
    total += (int)__popcll(mask);
  }
  int tt = total < NK ? total : NK;
  if (lane >= tt && lane < NK) s_idx[wid][lane] = s_idx[wid][0];
  int v = 0;
  if (lane < NK) {
    v = s_idx[wid][lane];
    idxball[(size_t)gid * NK + lane] = v;
    atomicAdd(&cnt[b * NPTS + v], 1);
  }
  float sx = 0.f, sy = 0.f, sz = 0.f;
  if (lane < NK) { sx = xb[v * 3 + 0]; sy = xb[v * 3 + 1]; sz = xb[v * 3 + 2]; }
#pragma unroll
  for (int off = 1; off < 64; off <<= 1) {
    sx += __shfl_xor(sx, off);
    sy += __shfl_xor(sy, off);
    sz += __shfl_xor(sz, off);
  }
  if (lane == 0) {
    atomicAdd(&emb[b * 96 + 0], sx - 32.0f * cx);
    atomicAdd(&emb[b * 96 + 1], sy - 32.0f * cy);
    atomicAdd(&emb[b * 96 + 2], sz - 32.0f * cz);
  }
}

// ---------------- emb feature part: emb[b,3+c] = sum_n cnt[b,n]*feat[b,c,n] ----
__global__ __launch_bounds__(256) void k_embfeat(const float* __restrict__ feat,
                                                 const int* __restrict__ cnt,
                                                 float* __restrict__ emb) {
  const int c = blockIdx.x, b = blockIdx.y;
  const float* f = feat + ((size_t)b * NC + c) * NPTS;
  const int* ct = cnt + b * NPTS;
  float acc = 0.f;
  for (int n = threadIdx.x; n < NPTS; n += 256)
    acc = fmaf((float)ct[n], f[n], acc);
  __shared__ float red[4];
#pragma unroll
  for (int off = 1; off < 64; off <<= 1) acc += __shfl_xor(acc, off);
  if ((threadIdx.x & 63) == 0) red[threadIdx.x >> 6] = acc;
  __syncthreads();
  if (threadIdx.x == 0)
    emb[b * 96 + 3 + c] = red[0] + red[1] + red[2] + red[3];
}

// ---------------- pe: proj + layernorm + exact gelu ----------------
__global__ __launch_bounds__(64) void k_pe(const float* __restrict__ prompt,
                                           const float* __restrict__ projw,
                                           const float* __restrict__ projb,
                                           const float* __restrict__ lng,
                                           const float* __restrict__ lnb,
                                           float* __restrict__ pe) {
  const int m = blockIdx.x, lane = threadIdx.x;
  const float p0 = prompt[m * 2 + 0], p1 = prompt[m * 2 + 1];
  const int c1 = lane, c2 = lane + 64;
  float v1 = p0 * projw[c1 * 2 + 0] + p1 * projw[c1 * 2 + 1] + projb[c1];
  float v2 = 0.f;
  if (c2 < NCP) v2 = p0 * projw[c2 * 2 + 0] + p1 * projw[c2 * 2 + 1] + projb[c2];
  float s = v1 + ((c2 < NCP) ? v2 : 0.f);
#pragma unroll
  for (int off = 1; off < 64; off <<= 1) s += __shfl_xor(s, off);
  float mu = s * (1.0f / 67.0f);
  float d1 = v1 - mu;
  float d2v = (c2 < NCP) ? (v2 - mu) : 0.f;
  float q = d1 * d1 + d2v * d2v;
#pragma unroll
  for (int off = 1; off < 64; off <<= 1) q += __shfl_xor(q, off);
  float inv = 1.0f / sqrtf(q * (1.0f / 67.0f) + 1e-5f);
  {
    float y = d1 * inv * lng[c1] + lnb[c1];
    pe[m * NCP + c1] = 0.5f * y * (1.0f + erff(y * 0.70710678118654752f));
  }
  if (c2 < NCP) {
    float y = (v2 - mu) * inv * lng[c2] + lnb[c2];
    pe[m * NCP + c2] = 0.5f * y * (1.0f + erff(y * 0.70710678118654752f));
  }
}

// ---------------- pw: softmax(emb/32768 @ pw_w.T + pw_b) ----------------
__global__ __launch_bounds__(1024) void k_pw(const float* __restrict__ emb,
                                             const float* __restrict__ pww,
                                             const float* __restrict__ pwb,
                                             float* __restrict__ pw) {
  const int b = blockIdx.x, m = threadIdx.x;
  __shared__ float se[NCP];
  __shared__ float red[16];
  __shared__ float bcast;
  if (m < NCP) se[m] = emb[b * 96 + m] * (1.0f / 32768.0f);
  __syncthreads();
  float acc = pwb[m];
  for (int c = 0; c < NCP; ++c) acc = fmaf(se[c], pww[m * NCP + c], acc);
  float mx = acc;
#pragma unroll
  for (int off = 1; off < 64; off <<= 1) mx = fmaxf(mx, __shfl_xor(mx, off));
  if ((m & 63) == 0) red[m >> 6] = mx;
  __syncthreads();
  if (m == 0) {
    float v = red[0];
    for (int w = 1; w < 16; ++w) v = fmaxf(v, red[w]);
    bcast = v;
  }
  __syncthreads();
  float e = expf(acc - bcast);
  float ssum = e;
#pragma unroll
  for (int off = 1; off < 64; off <<= 1) ssum += __shfl_xor(ssum, off);
  if ((m & 63) == 0) red[m >> 6] = ssum;
  __syncthreads();
  if (m == 0) {
    float v = 0.f;
    for (int w = 0; w < 16; ++w) v += red[w];
    bcast = v;
  }
  __syncthreads();
  pw[b * NM + m] = e / bcast;
}

// ---------------- fused gather + pe*pw + conv0 + conv1 + maxpool ----------------
__global__ __launch_bounds__(256) void k_main(const float* __restrict__ feat,
                                              const float* __restrict__ xyz,
                                              const float* __restrict__ newxyz,
                                              const int* __restrict__ idxball,
                                              const float* __restrict__ pe,
                                              const float* __restrict__ pwbuf,
                                              const float* __restrict__ w0t,
                                              const float* __restrict__ b0,
                                              const float* __restrict__ w1t,
                                              const float* __restrict__ b1,
                                              float* __restrict__ out) {
  __shared__ __align__(16) float g[NCP * 36];
  __shared__ __align__(16) float h0[128 * 36];
  __shared__ int s_idx[NK];
  __shared__ float spe[NCP];
  const int bid = blockIdx.x;
  const int b = bid >> 10, m = bid & 1023;
  const int t = threadIdx.x;
  const float pwv = pwbuf[bid];
  if (t < NK) {
    int n = idxball[(size_t)bid * NK + t];
    n = n < 0 ? 0 : (n > NPTS - 1 ? NPTS - 1 : n); // insurance clamp
    s_idx[t] = n;
  }
  if (t < NCP) spe[t] = pe[m * NCP + t] * pwv;
  __syncthreads();
  // stage feature rows of g (gather from native (B,C,N) layout; L3-resident)
  for (int e = t; e < NK * NC; e += 256) {
    int k = e >> 6, c = e & 63;
    int n = s_idx[k];
    g[(3 + c) * 36 + k] = feat[((size_t)b * NC + c) * NPTS + n] + spe[3 + c];
  }
  // stage xyz rows of g
  if (t < 96) {
    int k = t & 31, d = t >> 5;
    int n = s_idx[k];
    float cv = newxyz[bid * 3 + d];
    g[d * 36 + k] = (xyz[((size_t)b * NPTS + n) * 3 + d] - cv) + spe[d];
  }
  __syncthreads();
  // layer0: h0[o][k] = relu(sum_c W0[o,c]*g[c,k] + b0[o])
  {
    const int o = t & 127, kb = (t >> 7) * 16;
    float acc[16];
    float bb = b0[o];
#pragma unroll
    for (int j = 0; j < 16; ++j) acc[j] = bb;
    for (int c = 0; c < NCP; ++c) {
      float w = w0t[c * 128 + o];
      const float4* gp = reinterpret_cast<const float4*>(&g[c * 36 + kb]);
#pragma unroll
      for (int qq = 0; qq < 4; ++qq) {
        float4 gv = gp[qq];
        acc[qq * 4 + 0] = fmaf(w, gv.x, acc[qq * 4 + 0]);
        acc[qq * 4 + 1] = fmaf(w, gv.y, acc[qq * 4 + 1]);
        acc[qq * 4 + 2] = fmaf(w, gv.z, acc[qq * 4 + 2]);
        acc[qq * 4 + 3] = fmaf(w, gv.w, acc[qq * 4 + 3]);
      }
    }
    float4* hp = reinterpret_cast<float4*>(&h0[o * 36 + kb]);
#pragma unroll
    for (int qq = 0; qq < 4; ++qq) {
      float4 hv;
      hv.x = fmaxf(acc[qq * 4 + 0], 0.f);
      hv.y = fmaxf(acc[qq * 4 + 1], 0.f);
      hv.z = fmaxf(acc[qq * 4 + 2], 0.f);
      hv.w = fmaxf(acc[qq * 4 + 3], 0.f);
      hp[qq] = hv;
    }
  }
  __syncthreads();
  // layer1: pooled[o2] = max_k relu(sum_o W1[o2,o]*h0[o,k] + b1[o2])
  {
    const int o2 = t;
    float acc[32];
    float bb = b1[o2];
#pragma unroll
    for (int j = 0; j < 32; ++j) acc[j] = bb;
    for (int o = 0; o < 128; ++o) {
      float w = w1t[o * 256 + o2];
      const float4* hp = reinterpret_cast<const float4*>(&h0[o * 36]);
#pragma unroll
      for (int qq = 0; qq < 8; ++qq) {
        float4 hv = hp[qq];
        acc[qq * 4 + 0] = fmaf(w, hv.x, acc[qq * 4 + 0]);
        acc[qq * 4 + 1] = fmaf(w, hv.y, acc[qq * 4 + 1]);
        acc[qq * 4 + 2] = fmaf(w, hv.z, acc[qq * 4 + 2]);
        acc[qq * 4 + 3] = fmaf(w, hv.w, acc[qq * 4 + 3]);
      }
    }
    float mx = 0.f; // relu floor
#pragma unroll
    for (int k = 0; k < 32; ++k) mx = fmaxf(mx, acc[k]);
    out[OUT_POOLED + ((size_t)(b * 256 + o2)) * NM + m] = mx;
  }
}

extern "C" void kernel_launch(void* const* d_in, const int* in_sizes, int n_in,
                              void* d_out, int out_size, void* d_ws, size_t ws_size,
                              hipStream_t stream) {
  const float* xyz    = (const float*)d_in[0];
  const float* feat   = (const float*)d_in[1];
  const float* prompt = (const float*)d_in[2];
  const float* projw  = (const float*)d_in[3];
  const float* projb  = (const float*)d_in[4];
  const float* lng    = (const float*)d_in[5];
  const float* lnb    = (const float*)d_in[6];
  const float* pww    = (const float*)d_in[7];
  const float* pwb    = (const float*)d_in[8];
  const float* w0     = (const float*)d_in[9];
  const float* b0     = (const float*)d_in[10];
  const float* w1     = (const float*)d_in[11];
  const float* b1     = (const float*)d_in[12];
  float* ws = (float*)d_ws;
  float* out = (float*)d_out;

  float* w0t      = ws + OFF_W0T;
  float* w1t      = ws + OFF_W1T;
  float* nxyz     = ws + OFF_NEWXYZ;
  int*   idxball  = (int*)(ws + OFF_IDXBALL);
  int*   cnt      = (int*)(ws + OFF_CNT);
  float* emb      = ws + OFF_EMB;
  float* pwv      = ws + OFF_PW;
  float* pev      = ws + OFF_PE;
  float* sxw      = ws + OFF_SX;
  float* syw      = ws + OFF_SY;
  float* szw      = ws + OFF_SZ;
  unsigned* sklo  = (unsigned*)(ws + OFF_SKLO);

  hipMemsetAsync(cnt, 0, NB * NPTS * sizeof(int), stream);
  hipMemsetAsync(emb, 0, NB * 96 * sizeof(float), stream);

  k_prepw<<<128, 256, 0, stream>>>(w0, w1, w0t, w1t);
  k_sort<<<NB, 1024, 0, stream>>>(xyz, sxw, syw, szw, sklo);
  k_fps<<<NB, 512, 0, stream>>>(xyz, sxw, syw, szw, sklo, nxyz, out);
  k_ball<<<NB * NM / 4, 256, 0, stream>>>(xyz, nxyz, idxball, cnt, emb);
  k_embfeat<<<dim3(NC, NB), 256, 0, stream>>>(feat, cnt, emb);
  k_pe<<<NM, 64, 0, stream>>>(prompt, projw, projb, lng, lnb, pev);
  k_pw<<<NB, 1024, 0, stream>>>(emb, pww, pwb, pwv);
  k_main<<<NB * NM, 256, 0, stream>>>(feat, xyz, nxyz, idxball, pev, pwv,
                                      w0t, b0, w1t, b1, out);
}

// Round 16
// 1989.401 us; speedup vs baseline: 1.4775x; 1.4775x over previous
//
#include <hip/hip_runtime.h>
#include <hip/hip_bf16.h>

#define NB   4
#define NPTS 16384
#define NC   64
#define NM   1024
#define NK   32
#define NCP  67
#define RAD2 0.25f

// workspace offsets in 4-byte units (total ~323k floats = 1.29 MB)
#define OFF_W0T     0u        // 67*128 = 8576
#define OFF_W1T     8576u     // 128*256 = 32768
#define OFF_NEWXYZ  41344u    // 12288
#define OFF_IDXBALL 53632u    // 4*1024*32 = 131072 (int)
#define OFF_CNT     184704u   // 65536 (int)
#define OFF_EMB     250240u   // 384
#define OFF_PW      250624u   // 4096
#define OFF_PE      254720u   // 68608 -> ends 323328

// output offsets (FLOAT32 elements; d_out is float*)
#define OUT_NEWXYZ 0u
#define OUT_POOLED 12288u
#define OUT_IDX    1060864u

// ---------------- transpose weights ----------------
__global__ __launch_bounds__(256) void k_prepw(const float* __restrict__ w0,
                                               const float* __restrict__ w1,
                                               float* __restrict__ w0t,
                                               float* __restrict__ w1t) {
  int t = blockIdx.x * 256 + threadIdx.x;
  if (t < 128 * NCP) { int o = t / NCP, c = t % NCP; w0t[c * 128 + o] = w0[t]; }
  if (t < 256 * 128) { int o2 = t / 128, o = t % 128; w1t[o * 256 + o2] = w1[t]; }
}

// ---------------- furthest point sampling ----------------
// SESSION-BEST structure (r7, 1692us measured): one block per batch; 512
// threads, 32 points each (interleaved p = t+512*i). All coords + running
// min-dist in 128 NAMED scalar registers (allocator still spill-shuffles
// ~50 values at its ~96-VGPR grant — r8-r12 showed no knob changes that, and
// r13-r15 showed bucketized-pruning alternatives all pay MORE in coordination
// than they save in compute; this is the measured optimum for this session).
// Argmax via packed u64 key (f32bits<<32 | (16383-idx)): u64 max ==
// (max value, min index) — bit-identical to numpy/jax argmax incl. ties.
// Wave butterfly (u64 shfl) -> leader writes key -> one barrier -> all lanes
// fold 8 keys via broadcast LDS reads + in-register max; winner coords come
// from a broadcast global L2 load. Ping-ponged key buffer keeps WAR safe.
// Distances use explicit non-FMA f32 ops, (dx*dx+dy*dy)+dz*dz order.
__device__ __forceinline__ unsigned long long umax64(unsigned long long a,
                                                     unsigned long long b) {
  return a > b ? a : b;
}

#define FPS_DECL(i) float px##i, py##i, pz##i, md##i;
#define FPS_INIT(i) { int p = t + 512 * (i); \
  px##i = xb[p * 3 + 0]; py##i = xb[p * 3 + 1]; pz##i = xb[p * 3 + 2]; \
  md##i = 1e10f; }
#define FPS_UPD(i) { \
  float dx = __fsub_rn(px##i, lx); \
  float dy = __fsub_rn(py##i, ly); \
  float dz = __fsub_rn(pz##i, lz); \
  float d2 = __fadd_rn(__fadd_rn(__fmul_rn(dx, dx), __fmul_rn(dy, dy)), \
                       __fmul_rn(dz, dz)); \
  float m0 = fminf(md##i, d2); \
  md##i = m0; \
  bool gt = m0 > best; \
  best = gt ? m0 : best; \
  klo  = gt ? (kbase - 512u * (i)) : klo; }
#define FPS_REP32(M) M(0) M(1) M(2) M(3) M(4) M(5) M(6) M(7) \
  M(8) M(9) M(10) M(11) M(12) M(13) M(14) M(15) \
  M(16) M(17) M(18) M(19) M(20) M(21) M(22) M(23) \
  M(24) M(25) M(26) M(27) M(28) M(29) M(30) M(31)

__global__ __launch_bounds__(512, 1) void k_fps(const float* __restrict__ xyz,
                                                float* __restrict__ newxyz,
                                                float* __restrict__ out) {
  const int b = blockIdx.x;
  const int t = threadIdx.x;
  const float* xb = xyz + (size_t)b * NPTS * 3;
  __shared__ __align__(16) unsigned long long c_key[2][8];
  FPS_REP32(FPS_DECL)
  FPS_REP32(FPS_INIT)
  float lx = xb[0], ly = xb[1], lz = xb[2];
  if (t == 0) {
    newxyz[(size_t)b * NM * 3 + 0] = lx;
    newxyz[(size_t)b * NM * 3 + 1] = ly;
    newxyz[(size_t)b * NM * 3 + 2] = lz;
    out[OUT_NEWXYZ + (size_t)b * NM * 3 + 0] = lx;
    out[OUT_NEWXYZ + (size_t)b * NM * 3 + 1] = ly;
    out[OUT_NEWXYZ + (size_t)b * NM * 3 + 2] = lz;
    out[OUT_IDX + b * NM] = 0.0f;
  }
  __syncthreads();
  const int wid = t >> 6;
  const unsigned kbase = 16383u - (unsigned)t;   // klo = 16383 - idx
  for (int s = 1; s < NM; ++s) {
    float best = -1.0f;
    unsigned klo = 0u;
    FPS_REP32(FPS_UPD)
    unsigned long long kr =
        ((unsigned long long)__float_as_uint(best) << 32) |
        (unsigned long long)klo;
#pragma unroll
    for (int off = 1; off < 64; off <<= 1) {
      unsigned long long ok = __shfl_xor(kr, off);
      kr = ok > kr ? ok : kr;
    }
    const int pp = s & 1;
    if ((t & 63) == 0) c_key[pp][wid] = kr;
    __syncthreads();
    // fold 8 wave candidates: broadcast LDS reads + in-register u64 max
    const ulonglong2* ck = reinterpret_cast<const ulonglong2*>(&c_key[pp][0]);
    ulonglong2 k01 = ck[0], k23 = ck[1], k45 = ck[2], k67 = ck[3];
    unsigned long long k =
        umax64(umax64(umax64(k01.x, k01.y), umax64(k23.x, k23.y)),
               umax64(umax64(k45.x, k45.y), umax64(k67.x, k67.y)));
    const int bi = 16383 - (int)(unsigned)(k & 0xffffffffull);
    // broadcast L2 load of the winner's coords (same addr across lanes)
    lx = xb[bi * 3 + 0];
    ly = xb[bi * 3 + 1];
    lz = xb[bi * 3 + 2];
    if (t == 0) {
      newxyz[((size_t)b * NM + s) * 3 + 0] = lx;
      newxyz[((size_t)b * NM + s) * 3 + 1] = ly;
      newxyz[((size_t)b * NM + s) * 3 + 2] = lz;
      out[OUT_NEWXYZ + ((size_t)b * NM + s) * 3 + 0] = lx;
      out[OUT_NEWXYZ + ((size_t)b * NM + s) * 3 + 1] = ly;
      out[OUT_NEWXYZ + ((size_t)b * NM + s) * 3 + 2] = lz;
      out[OUT_IDX + b * NM + s] = (float)bi;
    }
  }
}

// ---------------- ball query: first NK indices with d2<=r2, pad with first ----
// one wave per (b,m); also histogram counts + xyz partial sums for emb.
__global__ __launch_bounds__(256) void k_ball(const float* __restrict__ xyz,
                                              const float* __restrict__ newxyz,
                                              int* __restrict__ idxball,
                                              int* __restrict__ cnt,
                                              float* __restrict__ emb) {
  __shared__ int s_idx[4][NK];
  const int lane = threadIdx.x & 63, wid = threadIdx.x >> 6;
  const int gid = blockIdx.x * 4 + wid; // (b,m)
  const int b = gid >> 10;
  const float* xb = xyz + (size_t)b * NPTS * 3;
  const float cx = newxyz[gid * 3 + 0];
  const float cy = newxyz[gid * 3 + 1];
  const float cz = newxyz[gid * 3 + 2];
  int total = 0;
  for (int base = 0; base < NPTS && total < NK; base += 64) {
    int n = base + lane;
    float dx = __fsub_rn(xb[n * 3 + 0], cx);
    float dy = __fsub_rn(xb[n * 3 + 1], cy);
    float dz = __fsub_rn(xb[n * 3 + 2], cz);
    float d2 = __fadd_rn(__fadd_rn(__fmul_rn(dx, dx), __fmul_rn(dy, dy)),
                         __fmul_rn(dz, dz));
    bool hit = d2 <= RAD2;
    unsigned long long mask = __ballot(hit);
    int pos = total + (int)__popcll(mask & ((1ull << lane) - 1ull));
    if (hit && pos < NK) s_idx[wid][pos] = n;
    total += (int)__popcll(mask);
  }
  int tt = total < NK ? total : NK;
  if (lane >= tt && lane < NK) s_idx[wid][lane] = s_idx[wid][0];
  int v = 0;
  if (lane < NK) {
    v = s_idx[wid][lane];
    idxball[(size_t)gid * NK + lane] = v;
    atomicAdd(&cnt[b * NPTS + v], 1);
  }
  float sx = 0.f, sy = 0.f, sz = 0.f;
  if (lane < NK) { sx = xb[v * 3 + 0]; sy = xb[v * 3 + 1]; sz = xb[v * 3 + 2]; }
#pragma unroll
  for (int off = 1; off < 64; off <<= 1) {
    sx += __shfl_xor(sx, off);
    sy += __shfl_xor(sy, off);
    sz += __shfl_xor(sz, off);
  }
  if (lane == 0) {
    atomicAdd(&emb[b * 96 + 0], sx - 32.0f * cx);
    atomicAdd(&emb[b * 96 + 1], sy - 32.0f * cy);
    atomicAdd(&emb[b * 96 + 2], sz - 32.0f * cz);
  }
}

// ---------------- emb feature part: emb[b,3+c] = sum_n cnt[b,n]*feat[b,c,n] ----
__global__ __launch_bounds__(256) void k_embfeat(const float* __restrict__ feat,
                                                 const int* __restrict__ cnt,
                                                 float* __restrict__ emb) {
  const int c = blockIdx.x, b = blockIdx.y;
  const float* f = feat + ((size_t)b * NC + c) * NPTS;
  const int* ct = cnt + b * NPTS;
  float acc = 0.f;
  for (int n = threadIdx.x; n < NPTS; n += 256)
    acc = fmaf((float)ct[n], f[n], acc);
  __shared__ float red[4];
#pragma unroll
  for (int off = 1; off < 64; off <<= 1) acc += __shfl_xor(acc, off);
  if ((threadIdx.x & 63) == 0) red[threadIdx.x >> 6] = acc;
  __syncthreads();
  if (threadIdx.x == 0)
    emb[b * 96 + 3 + c] = red[0] + red[1] + red[2] + red[3];
}

// ---------------- pe: proj + layernorm + exact gelu ----------------
__global__ __launch_bounds__(64) void k_pe(const float* __restrict__ prompt,
                                           const float* __restrict__ projw,
                                           const float* __restrict__ projb,
                                           const float* __restrict__ lng,
                                           const float* __restrict__ lnb,
                                           float* __restrict__ pe) {
  const int m = blockIdx.x, lane = threadIdx.x;
  const float p0 = prompt[m * 2 + 0], p1 = prompt[m * 2 + 1];
  const int c1 = lane, c2 = lane + 64;
  float v1 = p0 * projw[c1 * 2 + 0] + p1 * projw[c1 * 2 + 1] + projb[c1];
  float v2 = 0.f;
  if (c2 < NCP) v2 = p0 * projw[c2 * 2 + 0] + p1 * projw[c2 * 2 + 1] + projb[c2];
  float s = v1 + ((c2 < NCP) ? v2 : 0.f);
#pragma unroll
  for (int off = 1; off < 64; off <<= 1) s += __shfl_xor(s, off);
  float mu = s * (1.0f / 67.0f);
  float d1 = v1 - mu;
  float d2v = (c2 < NCP) ? (v2 - mu) : 0.f;
  float q = d1 * d1 + d2v * d2v;
#pragma unroll
  for (int off = 1; off < 64; off <<= 1) q += __shfl_xor(q, off);
  float inv = 1.0f / sqrtf(q * (1.0f / 67.0f) + 1e-5f);
  {
    float y = d1 * inv * lng[c1] + lnb[c1];
    pe[m * NCP + c1] = 0.5f * y * (1.0f + erff(y * 0.70710678118654752f));
  }
  if (c2 < NCP) {
    float y = (v2 - mu) * inv * lng[c2] + lnb[c2];
    pe[m * NCP + c2] = 0.5f * y * (1.0f + erff(y * 0.70710678118654752f));
  }
}

// ---------------- pw: softmax(emb/32768 @ pw_w.T + pw_b) ----------------
__global__ __launch_bounds__(1024) void k_pw(const float* __restrict__ emb,
                                             const float* __restrict__ pww,
                                             const float* __restrict__ pwb,
                                             float* __restrict__ pw) {
  const int b = blockIdx.x, m = threadIdx.x;
  __shared__ float se[NCP];
  __shared__ float red[16];
  __shared__ float bcast;
  if (m < NCP) se[m] = emb[b * 96 + m] * (1.0f / 32768.0f);
  __syncthreads();
  float acc = pwb[m];
  for (int c = 0; c < NCP; ++c) acc = fmaf(se[c], pww[m * NCP + c], acc);
  float mx = acc;
#pragma unroll
  for (int off = 1; off < 64; off <<= 1) mx = fmaxf(mx, __shfl_xor(mx, off));
  if ((m & 63) == 0) red[m >> 6] = mx;
  __syncthreads();
  if (m == 0) {
    float v = red[0];
    for (int w = 1; w < 16; ++w) v = fmaxf(v, red[w]);
    bcast = v;
  }
  __syncthreads();
  float e = expf(acc - bcast);
  float ssum = e;
#pragma unroll
  for (int off = 1; off < 64; off <<= 1) ssum += __shfl_xor(ssum, off);
  if ((m & 63) == 0) red[m >> 6] = ssum;
  __syncthreads();
  if (m == 0) {
    float v = 0.f;
    for (int w = 0; w < 16; ++w) v += red[w];
    bcast = v;
  }
  __syncthreads();
  pw[b * NM + m] = e / bcast;
}

// ---------------- fused gather + pe*pw + conv0 + conv1 + maxpool ----------------
__global__ __launch_bounds__(256) void k_main(const float* __restrict__ feat,
                                              const float* __restrict__ xyz,
                                              const float* __restrict__ newxyz,
                                              const int* __restrict__ idxball,
                                              const float* __restrict__ pe,
                                              const float* __restrict__ pwbuf,
                                              const float* __restrict__ w0t,
                                              const float* __restrict__ b0,
                                              const float* __restrict__ w1t,
                                              const float* __restrict__ b1,
                                              float* __restrict__ out) {
  __shared__ __align__(16) float g[NCP * 36];
  __shared__ __align__(16) float h0[128 * 36];
  __shared__ int s_idx[NK];
  __shared__ float spe[NCP];
  const int bid = blockIdx.x;
  const int b = bid >> 10, m = bid & 1023;
  const int t = threadIdx.x;
  const float pwv = pwbuf[bid];
  if (t < NK) {
    int n = idxball[(size_t)bid * NK + t];
    n = n < 0 ? 0 : (n > NPTS - 1 ? NPTS - 1 : n); // insurance clamp
    s_idx[t] = n;
  }
  if (t < NCP) spe[t] = pe[m * NCP + t] * pwv;
  __syncthreads();
  // stage feature rows of g (gather from native (B,C,N) layout; L3-resident)
  for (int e = t; e < NK * NC; e += 256) {
    int k = e >> 6, c = e & 63;
    int n = s_idx[k];
    g[(3 + c) * 36 + k] = feat[((size_t)b * NC + c) * NPTS + n] + spe[3 + c];
  }
  // stage xyz rows of g
  if (t < 96) {
    int k = t & 31, d = t >> 5;
    int n = s_idx[k];
    float cv = newxyz[bid * 3 + d];
    g[d * 36 + k] = (xyz[((size_t)b * NPTS + n) * 3 + d] - cv) + spe[d];
  }
  __syncthreads();
  // layer0: h0[o][k] = relu(sum_c W0[o,c]*g[c,k] + b0[o])
  {
    const int o = t & 127, kb = (t >> 7) * 16;
    float acc[16];
    float bb = b0[o];
#pragma unroll
    for (int j = 0; j < 16; ++j) acc[j] = bb;
    for (int c = 0; c < NCP; ++c) {
      float w = w0t[c * 128 + o];
      const float4* gp = reinterpret_cast<const float4*>(&g[c * 36 + kb]);
#pragma unroll
      for (int qq = 0; qq < 4; ++qq) {
        float4 gv = gp[qq];
        acc[qq * 4 + 0] = fmaf(w, gv.x, acc[qq * 4 + 0]);
        acc[qq * 4 + 1] = fmaf(w, gv.y, acc[qq * 4 + 1]);
        acc[qq * 4 + 2] = fmaf(w, gv.z, acc[qq * 4 + 2]);
        acc[qq * 4 + 3] = fmaf(w, gv.w, acc[qq * 4 + 3]);
      }
    }
    float4* hp = reinterpret_cast<float4*>(&h0[o * 36 + kb]);
#pragma unroll
    for (int qq = 0; qq < 4; ++qq) {
      float4 hv;
      hv.x = fmaxf(acc[qq * 4 + 0], 0.f);
      hv.y = fmaxf(acc[qq * 4 + 1], 0.f);
      hv.z = fmaxf(acc[qq * 4 + 2], 0.f);
      hv.w = fmaxf(acc[qq * 4 + 3], 0.f);
      hp[qq] = hv;
    }
  }
  __syncthreads();
  // layer1: pooled[o2] = max_k relu(sum_o W1[o2,o]*h0[o,k] + b1[o2])
  {
    const int o2 = t;
    float acc[32];
    float bb = b1[o2];
#pragma unroll
    for (int j = 0; j < 32; ++j) acc[j] = bb;
    for (int o = 0; o < 128; ++o) {
      float w = w1t[o * 256 + o2];
      const float4* hp = reinterpret_cast<const float4*>(&h0[o * 36]);
#pragma unroll
      for (int qq = 0; qq < 8; ++qq) {
        float4 hv = hp[qq];
        acc[qq * 4 + 0] = fmaf(w, hv.x, acc[qq * 4 + 0]);
        acc[qq * 4 + 1] = fmaf(w, hv.y, acc[qq * 4 + 1]);
        acc[qq * 4 + 2] = fmaf(w, hv.z, acc[qq * 4 + 2]);
        acc[qq * 4 + 3] = fmaf(w, hv.w, acc[qq * 4 + 3]);
      }
    }
    float mx = 0.f; // relu floor
#pragma unroll
    for (int k = 0; k < 32; ++k) mx = fmaxf(mx, acc[k]);
    out[OUT_POOLED + ((size_t)(b * 256 + o2)) * NM + m] = mx;
  }
}

extern "C" void kernel_launch(void* const* d_in, const int* in_sizes, int n_in,
                              void* d_out, int out_size, void* d_ws, size_t ws_size,
                              hipStream_t stream) {
  const float* xyz    = (const float*)d_in[0];
  const float* feat   = (const float*)d_in[1];
  const float* prompt = (const float*)d_in[2];
  const float* projw  = (const float*)d_in[3];
  const float* projb  = (const float*)d_in[4];
  const float* lng    = (const float*)d_in[5];
  const float* lnb    = (const float*)d_in[6];
  const float* pww    = (const float*)d_in[7];
  const float* pwb    = (const float*)d_in[8];
  const float* w0     = (const float*)d_in[9];
  const float* b0     = (const float*)d_in[10];
  const float* w1     = (const float*)d_in[11];
  const float* b1     = (const float*)d_in[12];
  float* ws = (float*)d_ws;
  float* out = (float*)d_out;

  float* w0t     = ws + OFF_W0T;
  float* w1t     = ws + OFF_W1T;
  float* nxyz    = ws + OFF_NEWXYZ;
  int*   idxball = (int*)(ws + OFF_IDXBALL);
  int*   cnt     = (int*)(ws + OFF_CNT);
  float* emb     = ws + OFF_EMB;
  float* pwv     = ws + OFF_PW;
  float* pev     = ws + OFF_PE;

  hipMemsetAsync(cnt, 0, NB * NPTS * sizeof(int), stream);
  hipMemsetAsync(emb, 0, NB * 96 * sizeof(float), stream);

  k_prepw<<<128, 256, 0, stream>>>(w0, w1, w0t, w1t);
  k_fps<<<NB, 512, 0, stream>>>(xyz, nxyz, out);
  k_ball<<<NB * NM / 4, 256, 0, stream>>>(xyz, nxyz, idxball, cnt, emb);
  k_embfeat<<<dim3(NC, NB), 256, 0, stream>>>(feat, cnt, emb);
  k_pe<<<NM, 64, 0, stream>>>(prompt, projw, projb, lng, lnb, pev);
  k_pw<<<NB, 1024, 0, stream>>>(emb, pww, pwb, pwv);
  k_main<<<NB * NM, 256, 0, stream>>>(feat, xyz, nxyz, idxball, pev, pwv,
                                      w0t, b0, w1t, b1, out);
}